// Round 8
// baseline (275.788 us; speedup 1.0000x reference)
//
#include <hip/hip_runtime.h>

#define SEQ 2048
#define DIM 1024
#define NHEAD 16
#define HDIM 64
#define NTOK 4096   // b*s
#define N3D 3072

typedef __attribute__((ext_vector_type(8))) short bf16x8;
typedef __attribute__((ext_vector_type(4))) short bf16x4;
typedef __attribute__((ext_vector_type(4))) float floatx4;
typedef __attribute__((ext_vector_type(4))) unsigned short ushortx4;
typedef __attribute__((ext_vector_type(2))) int intx2;

__device__ __forceinline__ unsigned short f2bf(float f) {
    unsigned int u = __builtin_bit_cast(unsigned int, f);
    u += 0x7FFFu + ((u >> 16) & 1u);
    return (unsigned short)(u >> 16);
}

__device__ __forceinline__ unsigned int pack_bf16(float a, float b) {
    return (unsigned int)f2bf(a) | ((unsigned int)f2bf(b) << 16);
}

// async global->LDS, 16B per lane. LDS dest must be wave-uniform base + lane*16.
__device__ __forceinline__ void async_copy16(const void* g, const void* l) {
    __builtin_amdgcn_global_load_lds(
        (const __attribute__((address_space(1))) unsigned int*)(unsigned long long)g,
        (__attribute__((address_space(3))) unsigned int*)(unsigned int)(unsigned long long)l,
        16, 0, 0);
}

#define MFMA_BF16(a, b, c) __builtin_amdgcn_mfma_f32_16x16x32_bf16((a), (b), (c), 0, 0, 0)
// v_mfma_f32_16x16x16_bf16 (cdna4_isa.md §10: A=2, B=2, C/D=4 regs).
// NOTE: do NOT guard with __has_builtin — false in the HIP host pass (r6 lesson).
#define MFMA16(a, b, c) __builtin_amdgcn_mfma_f32_16x16x16bf16_1k((a), (b), (c), 0, 0, 0)

// ---------------------------------------------------------------------------
// Bias table init: gt[t] = {f(t), f(t+1)}, f(d) = beta*log1p(d)*log2e - 20
// ---------------------------------------------------------------------------
__global__ __launch_bounds__(256)
void bias_init(const float* __restrict__ betap, float2* __restrict__ gt) {
    const int i = blockIdx.x * 256 + threadIdx.x;
    if (i >= SEQ) return;
    const float b = betap[0];
    const float L2E = 1.44269504f;
    float fa = b * log1pf((float)i) * L2E - 20.0f;
    int i1 = (i + 1 < SEQ) ? i + 1 : SEQ - 1;
    float fb = b * log1pf((float)i1) * L2E - 20.0f;
    gt[i] = make_float2(fa, fb);
}

// ---------------------------------------------------------------------------
// Transpose + fp32->bf16 cast: src [rows][cols] f32 -> dst [cols][rows] bf16
// ---------------------------------------------------------------------------
__global__ __launch_bounds__(256)
void transpose_cvt(const float* __restrict__ src, unsigned short* __restrict__ dst,
                   int rows, int cols) {
    __shared__ float tile[32][33];
    const int c0 = blockIdx.x * 32, r0 = blockIdx.y * 32;
    const int tx = threadIdx.x & 31, ty = threadIdx.x >> 5;  // 32 x 8
    for (int i = 0; i < 4; ++i) {
        int r = ty + i * 8;
        tile[r][tx] = src[(size_t)(r0 + r) * cols + c0 + tx];
    }
    __syncthreads();
    for (int i = 0; i < 4; ++i) {
        int rr = ty + i * 8;  // col index in src
        dst[(size_t)(c0 + rr) * rows + r0 + tx] = f2bf(tile[tx][rr]);
    }
}

// ---------------------------------------------------------------------------
// LayerNorm: x [4096][1024] f32 -> xn bf16
// ---------------------------------------------------------------------------
__global__ __launch_bounds__(256)
void ln_kernel(const float* __restrict__ x, const float* __restrict__ gamma,
               const float* __restrict__ lnb, unsigned short* __restrict__ xn) {
    const int row = blockIdx.x;
    const int tid = threadIdx.x;
    const float* xr = x + (size_t)row * DIM;
    float4 v = ((const float4*)xr)[tid];
    float s = v.x + v.y + v.z + v.w;
    float s2 = v.x * v.x + v.y * v.y + v.z * v.z + v.w * v.w;
    for (int off = 1; off < 64; off <<= 1) {
        s += __shfl_xor(s, off, 64);
        s2 += __shfl_xor(s2, off, 64);
    }
    __shared__ float red[8];
    const int wave = tid >> 6, lane = tid & 63;
    if (lane == 0) { red[wave] = s; red[4 + wave] = s2; }
    __syncthreads();
    s = red[0] + red[1] + red[2] + red[3];
    s2 = red[4] + red[5] + red[6] + red[7];
    const float mu = s * (1.0f / DIM);
    const float var = s2 * (1.0f / DIM) - mu * mu;
    const float rstd = rsqrtf(var + 1e-5f);
    float4 g = ((const float4*)gamma)[tid];
    float4 bb = ((const float4*)lnb)[tid];
    unsigned short* o = xn + (size_t)row * DIM + tid * 4;
    o[0] = f2bf((v.x - mu) * rstd * g.x + bb.x);
    o[1] = f2bf((v.y - mu) * rstd * g.y + bb.y);
    o[2] = f2bf((v.z - mu) * rstd * g.z + bb.z);
    o[3] = f2bf((v.w - mu) * rstd * g.w + bb.w);
}

// ---------------------------------------------------------------------------
// QKV GEMM (BT form): A=xn [4096][1024], Bt=wqkvT [3072][1024], both bf16.
// Scatters q,k -> [b,h,s,hd]; v -> [b,h,hd,s] (transposed for attention PV).
// ---------------------------------------------------------------------------
__global__ __launch_bounds__(256)
void qkv_gemm(const unsigned short* __restrict__ A, const unsigned short* __restrict__ Bt,
              const float* __restrict__ bias, unsigned short* __restrict__ qo,
              unsigned short* __restrict__ ko, unsigned short* __restrict__ vTo) {
    __shared__ unsigned short Asm[128 * 32];
    __shared__ unsigned short Bsm[128 * 32];
    const int tid = threadIdx.x;
    const int wave = tid >> 6, lane = tid & 63;
    const int quad = lane >> 4, r16 = lane & 15;
    const int m0 = blockIdx.y * 128, n0 = blockIdx.x * 128;
    const int wm = (wave & 1) * 64, wn = (wave >> 1) * 64;
    floatx4 acc[4][4] = {};
    for (int k0 = 0; k0 < DIM; k0 += 32) {
        __syncthreads();
        for (int p = 0; p < 2; ++p) {
            int s = tid + p * 256;
            int r = s >> 2, c8 = (s & 3) << 3;
            async_copy16(A + (size_t)(m0 + r) * DIM + k0 + c8, Asm + s * 8);
            async_copy16(Bt + (size_t)(n0 + r) * DIM + k0 + c8, Bsm + s * 8);
        }
        __syncthreads();
        bf16x8 af[4], bfr[4];
        for (int i = 0; i < 4; ++i)
            af[i] = *(const bf16x8*)(Asm + (wm + i * 16 + r16) * 32 + quad * 8);
        for (int j = 0; j < 4; ++j)
            bfr[j] = *(const bf16x8*)(Bsm + (wn + j * 16 + r16) * 32 + quad * 8);
        for (int i = 0; i < 4; ++i)
            for (int j = 0; j < 4; ++j)
                acc[i][j] = MFMA_BF16(af[i], bfr[j], acc[i][j]);
    }
    for (int j = 0; j < 4; ++j) {
        int n = n0 + wn + j * 16 + r16;
        float bn = bias[n];
        int part = n >> 10, nn = n & 1023;
        int head = nn >> 6, hdi = nn & 63;
        for (int i = 0; i < 4; ++i) {
            int mbase = m0 + wm + i * 16 + quad * 4;
            int bIdx = mbase >> 11, sIdx = mbase & 2047;
            if (part == 2) {
                ushortx4 pack;
                for (int e = 0; e < 4; ++e) pack[e] = f2bf(acc[i][j][e] + bn);
                *(ushortx4*)(vTo + ((size_t)(bIdx * NHEAD + head) * HDIM + hdi) * SEQ + sIdx) = pack;
            } else {
                unsigned short* dst = (part == 0) ? qo : ko;
                for (int e = 0; e < 4; ++e)
                    dst[((size_t)(bIdx * NHEAD + head) * SEQ + sIdx + e) * HDIM + hdi] =
                        f2bf(acc[i][j][e] + bn);
            }
        }
    }
}

// ---------------------------------------------------------------------------
// Flash attention, round-8: r7 inner loop + occupancy restored.
//  - 512 threads = 8 waves, IN-BLOCK K-SPLIT: waves 0-3 do keys [0,1024),
//    waves 4-7 keys [1024,2048), same 128 queries. Merge via LDS at the end
//    (fixed-offset softmax -> merge is pure o+=o', l+=l').
//  - 4 double-buffered 8KB chunk buffers (K,V per group) = 64KB LDS
//    -> 2 blocks/CU -> 16 waves/CU (launch_bounds(512,4): VGPR cap 128).
//  - bias table in GLOBAL memory (VMEM pipe, L1/L2-resident; off the
//    contended LDS pipe; loads are index-only -> overlap the S^T MFMAs).
//  - S^T = K·Q^T; PV consumes P direct from regs (16x16x16 B-operand ==
//    S^T C-layout); O^T = V^T·P^T; l via ones-A-frag; XOR-swizzled LDS.
// grid (SEQ/128, B*NHEAD), 512 threads.
// ---------------------------------------------------------------------------
__global__ __launch_bounds__(512, 4)
void attn_kernel(const unsigned short* __restrict__ qg, const unsigned short* __restrict__ kg,
                 const unsigned short* __restrict__ vTg, const float2* __restrict__ gt,
                 unsigned short* __restrict__ ctx) {
    __shared__ unsigned short Kd[2][2][4096];   // [group][buf], swizzled, rows=key
    __shared__ unsigned short Vd[2][2][4096];   // [group][buf], swizzled, rows=d (V^T)

    const int tid = threadIdx.x;
    const int wave = tid >> 6, lane = tid & 63;
    const int quad = lane >> 4, r16 = lane & 15;
    const int grp = wave >> 2, wq = wave & 3;   // key-group, query-wave
    const int bh = blockIdx.y, qt = blockIdx.x;
    const int qBase = qt * 128;
    const float c1 = 0.125f * 1.44269504f;
    const float* Ffg = (const float*)gt;        // Ffg[2d] = f(d)

    // Q fragments direct from global: B-operand (n=r16 -> q row, k octet = quad)
    bf16x8 qf[2][2];
    {
        const unsigned short* qp0 =
            qg + ((size_t)bh * SEQ + qBase + wq * 32 + r16) * HDIM;
        qf[0][0] = *(const bf16x8*)(qp0 + quad * 8);
        qf[0][1] = *(const bf16x8*)(qp0 + 32 + quad * 8);
        const unsigned short* qp1 = qp0 + 16 * HDIM;
        qf[1][0] = *(const bf16x8*)(qp1 + quad * 8);
        qf[1][1] = *(const bf16x8*)(qp1 + 32 + quad * 8);
    }

    // cooperative staging (all 512 threads stage both groups' chunks)
    // swizzle: row r, colgrp cg stored at slot cg^(r&7)
    const int sr = tid >> 3;                    // 0..63
    const int scg = (tid & 7) ^ (sr & 7);
    const unsigned short* kbh = kg + (size_t)bh * SEQ * HDIM;
    const unsigned short* vbh = vTg + (size_t)bh * HDIM * SEQ;
    // chunk 0 of each group into buf 0
    async_copy16(kbh + (size_t)sr * HDIM + scg * 8, &Kd[0][0][tid * 8]);
    async_copy16(kbh + (size_t)(1024 + sr) * HDIM + scg * 8, &Kd[1][0][tid * 8]);
    async_copy16(vbh + (size_t)sr * SEQ + scg * 8, &Vd[0][0][tid * 8]);
    async_copy16(vbh + (size_t)sr * SEQ + 1024 + scg * 8, &Vd[1][0][tid * 8]);
    __syncthreads();

    const bf16x4 ones4 = {0x3F80, 0x3F80, 0x3F80, 0x3F80};

    floatx4 o[2][4] = {};   // O^T accum: [qn][nt], lane: q=r16, d=nt*16+quad*4+i
    floatx4 o4[2] = {};     // row-sum l (ones trick)
    const int qWB0 = qBase + wq * 32;            // wave-uniform, qn=0
    const int qrow0 = qWB0 + r16;                // per-lane query, qn=0
    const int kGrpBase = grp << 10;

    for (int it = 0; it < 16; ++it) {
        const int buf = it & 1;
        if (it + 1 < 16) {
            const int nk = (it + 1) << 6;        // next chunk offset within group
            async_copy16(kbh + (size_t)(nk + sr) * HDIM + scg * 8, &Kd[0][buf ^ 1][tid * 8]);
            async_copy16(kbh + (size_t)(1024 + nk + sr) * HDIM + scg * 8, &Kd[1][buf ^ 1][tid * 8]);
            async_copy16(vbh + (size_t)sr * SEQ + nk + scg * 8, &Vd[0][buf ^ 1][tid * 8]);
            async_copy16(vbh + (size_t)sr * SEQ + 1024 + nk + scg * 8, &Vd[1][buf ^ 1][tid * 8]);
        }
        const int kt0 = kGrpBase + (it << 6);

        // S^T = K·Q^T, K frags shared across both q-groups
        floatx4 sc[2][4];
        for (int ct = 0; ct < 4; ++ct) {
            int rK = ct * 16 + r16;
            const unsigned short* kb = &Kd[grp][buf][rK * 64];
            bf16x8 kf0 = *(const bf16x8*)(kb + ((quad ^ (rK & 7)) << 3));
            bf16x8 kf1 = *(const bf16x8*)(kb + (((quad ^ 4) ^ (rK & 7)) << 3));
            for (int qn = 0; qn < 2; ++qn) {
                floatx4 z = {0.f, 0.f, 0.f, 0.f};
                z = MFMA_BF16(kf0, qf[qn][0], z);
                z = MFMA_BF16(kf1, qf[qn][1], z);
                sc[qn][ct] = z;
            }
        }
        // bias (global paired table) + exp2 -> P packed into B-operand regs
        bf16x4 pk[2][4];
        for (int qn = 0; qn < 2; ++qn) {
            const int qWB = qWB0 + qn * 16;
            const int qrow = qrow0 + qn * 16;
            for (int ct = 0; ct < 4; ++ct) {
                const int keyTile = kt0 + ct * 16;   // wave-uniform
                const int key0 = keyTile + quad * 4; // per-lane key base
                floatx4 s = sc[qn][ct];
                if (qWB >= keyTile + 16) {            // all queries > all keys
                    int dlo = qrow - key0 - 3;
                    float2 a = gt[dlo], b = gt[dlo + 2];
                    s[0] = __builtin_amdgcn_exp2f(s[0] * c1 + b.y);
                    s[1] = __builtin_amdgcn_exp2f(s[1] * c1 + b.x);
                    s[2] = __builtin_amdgcn_exp2f(s[2] * c1 + a.y);
                    s[3] = __builtin_amdgcn_exp2f(s[3] * c1 + a.x);
                } else if (keyTile >= qWB + 16) {     // all keys > all queries
                    int dlo = key0 - qrow;
                    float2 a = gt[dlo], b = gt[dlo + 2];
                    s[0] = __builtin_amdgcn_exp2f(s[0] * c1 + a.x);
                    s[1] = __builtin_amdgcn_exp2f(s[1] * c1 + a.y);
                    s[2] = __builtin_amdgcn_exp2f(s[2] * c1 + b.x);
                    s[3] = __builtin_amdgcn_exp2f(s[3] * c1 + b.y);
                } else {                               // mixed (diagonal tiles)
                    for (int i = 0; i < 4; ++i) {
                        int d = key0 + i - qrow;
                        d = d < 0 ? -d : d;
                        s[i] = __builtin_amdgcn_exp2f(s[i] * c1 + Ffg[2 * d]);
                    }
                }
                intx2 u = {(int)pack_bf16(s[0], s[1]), (int)pack_bf16(s[2], s[3])};
                pk[qn][ct] = __builtin_bit_cast(bf16x4, u);
            }
        }
        // O^T += V^T·P^T  (MFMA16; V^T frags shared across q-groups)
        for (int ks = 0; ks < 4; ++ks) {
            o4[0] = MFMA16(ones4, pk[0][ks], o4[0]);
            o4[1] = MFMA16(ones4, pk[1][ks], o4[1]);
            for (int nt = 0; nt < 4; ++nt) {
                int rV = nt * 16 + r16;
                const unsigned short* vb = &Vd[grp][buf][rV * 64];
                bf16x4 vf = *(const bf16x4*)(vb +
                    (((ks * 2 + (quad >> 1)) ^ (rV & 7)) << 3) + ((quad & 1) << 2));
                o[0][nt] = MFMA16(vf, pk[0][ks], o[0][nt]);
                o[1][nt] = MFMA16(vf, pk[1][ks], o[1][nt]);
            }
        }
        __syncthreads();
    }

    // merge the two key-groups through the (now dead) K/V LDS
    float* KdF = (float*)Kd;   // 8192 floats
    float* VdF = (float*)Vd;
    if (grp == 1) {
        const int base = wq * 2048 + lane * 32;
        for (int qn = 0; qn < 2; ++qn)
            for (int nt = 0; nt < 4; ++nt)
                *(floatx4*)(KdF + base + (qn * 4 + nt) * 4) = o[qn][nt];
        VdF[wq * 128 + lane * 2 + 0] = o4[0][0];
        VdF[wq * 128 + lane * 2 + 1] = o4[1][0];
    }
    __syncthreads();
    if (grp == 0) {
        const int base = wq * 2048 + lane * 32;
        const int b_ = bh >> 4, h_ = bh & 15;
        for (int qn = 0; qn < 2; ++qn) {
            float l = o4[qn][0] + VdF[wq * 128 + lane * 2 + qn];
            float inv = 1.0f / l;
            int q = qBase + wq * 32 + qn * 16 + r16;
            size_t obase = ((size_t)(b_ * SEQ + q)) * DIM + h_ * HDIM;
            for (int nt = 0; nt < 4; ++nt) {
                floatx4 add = *(const floatx4*)(KdF + base + (qn * 4 + nt) * 4);
                floatx4 t = o[qn][nt] + add;
                ushortx4 pck;
                for (int i = 0; i < 4; ++i) pck[i] = f2bf(t[i] * inv);
                *(ushortx4*)(ctx + obase + nt * 16 + quad * 4) = pck;
            }
        }
    }
}

// ---------------------------------------------------------------------------
// Out projection + bias + residual: out = ctx @ w_out + b_out + x  (fp32 out)
// 128(M)x64(N) tiles -> 512 blocks (2/CU).
// ---------------------------------------------------------------------------
__global__ __launch_bounds__(256)
void out_gemm(const unsigned short* __restrict__ A, const unsigned short* __restrict__ Bt,
              const float* __restrict__ bias, const float* __restrict__ resid,
              float* __restrict__ out) {
    __shared__ unsigned short Asm[128 * 32];
    __shared__ unsigned short Bsm[64 * 32];
    const int tid = threadIdx.x;
    const int wave = tid >> 6, lane = tid & 63;
    const int quad = lane >> 4, r16 = lane & 15;
    const int m0 = blockIdx.y * 128, n0 = blockIdx.x * 64;
    const int wm = (wave & 1) * 64, wn = (wave >> 1) * 32;
    floatx4 acc[4][2] = {};
    for (int k0 = 0; k0 < DIM; k0 += 32) {
        __syncthreads();
        for (int p = 0; p < 2; ++p) {
            int s = tid + p * 256;
            int r = s >> 2, c8 = (s & 3) << 3;
            async_copy16(A + (size_t)(m0 + r) * DIM + k0 + c8, Asm + s * 8);
        }
        {
            int r = tid >> 2, c8 = (tid & 3) << 3;
            async_copy16(Bt + (size_t)(n0 + r) * DIM + k0 + c8, Bsm + tid * 8);
        }
        __syncthreads();
        bf16x8 af[4], bfr[2];
        for (int i = 0; i < 4; ++i)
            af[i] = *(const bf16x8*)(Asm + (wm + i * 16 + r16) * 32 + quad * 8);
        for (int j = 0; j < 2; ++j)
            bfr[j] = *(const bf16x8*)(Bsm + (wn + j * 16 + r16) * 32 + quad * 8);
        for (int i = 0; i < 4; ++i)
            for (int j = 0; j < 2; ++j)
                acc[i][j] = MFMA_BF16(af[i], bfr[j], acc[i][j]);
    }
    for (int i = 0; i < 4; ++i)
        for (int j = 0; j < 2; ++j)
            for (int e = 0; e < 4; ++e) {
                int m = m0 + wm + i * 16 + quad * 4 + e;
                int n = n0 + wn + j * 16 + r16;
                out[(size_t)m * DIM + n] = acc[i][j][e] + bias[n] + resid[(size_t)m * DIM + n];
            }
}

// ---------------------------------------------------------------------------
extern "C" void kernel_launch(void* const* d_in, const int* in_sizes, int n_in,
                              void* d_out, int out_size, void* d_ws, size_t ws_size,
                              hipStream_t stream) {
    const float* x     = (const float*)d_in[0];
    const float* w_qkv = (const float*)d_in[1];
    const float* b_qkv = (const float*)d_in[2];
    const float* w_out = (const float*)d_in[3];
    const float* b_out = (const float*)d_in[4];
    const float* gamma = (const float*)d_in[5];
    const float* ln_b  = (const float*)d_in[6];
    const float* beta  = (const float*)d_in[7];
    float* out = (float*)d_out;

    char* ws = (char*)d_ws;
    const size_t MB = 1u << 20;
    unsigned short* xn    = (unsigned short*)(ws);            // 8 MB (reused as ctx)
    unsigned short* wqkvT = (unsigned short*)(ws + 8 * MB);   // 6 MB
    unsigned short* woutT = (unsigned short*)(ws + 14 * MB);  // 2 MB
    unsigned short* qb    = (unsigned short*)(ws + 16 * MB);  // 8 MB
    unsigned short* kb    = (unsigned short*)(ws + 24 * MB);  // 8 MB
    unsigned short* vTb   = (unsigned short*)(ws + 32 * MB);  // 8 MB
    float2*         gt    = (float2*)(ws + 40 * MB);          // 16 KB bias table
    unsigned short* ctx   = xn;  // xn dead after qkv_gemm; safe alias (stream-ordered)

    bias_init<<<dim3(8), 256, 0, stream>>>(beta, gt);
    transpose_cvt<<<dim3(96, 32), 256, 0, stream>>>(w_qkv, wqkvT, DIM, N3D);
    transpose_cvt<<<dim3(32, 32), 256, 0, stream>>>(w_out, woutT, DIM, DIM);
    ln_kernel<<<NTOK, 256, 0, stream>>>(x, gamma, ln_b, xn);
    qkv_gemm<<<dim3(24, 32), 256, 0, stream>>>(xn, wqkvT, b_qkv, qb, kb, vTb);
    attn_kernel<<<dim3(SEQ / 128, 32), 512, 0, stream>>>(qb, kb, vTb, gt, ctx);
    out_gemm<<<dim3(16, 32), 256, 0, stream>>>(ctx, woutT, b_out, x, out);
}

// Round 9
// 237.006 us; speedup vs baseline: 1.1636x; 1.1636x over previous
//
#include <hip/hip_runtime.h>

#define SEQ 2048
#define DIM 1024
#define NHEAD 16
#define HDIM 64
#define NTOK 4096   // b*s
#define N3D 3072

typedef __attribute__((ext_vector_type(8))) short bf16x8;
typedef __attribute__((ext_vector_type(4))) short bf16x4;
typedef __attribute__((ext_vector_type(4))) float floatx4;
typedef __attribute__((ext_vector_type(4))) unsigned short ushortx4;
typedef __attribute__((ext_vector_type(2))) int intx2;

__device__ __forceinline__ unsigned short f2bf(float f) {
    unsigned int u = __builtin_bit_cast(unsigned int, f);
    u += 0x7FFFu + ((u >> 16) & 1u);
    return (unsigned short)(u >> 16);
}

__device__ __forceinline__ unsigned int pack_bf16(float a, float b) {
    return (unsigned int)f2bf(a) | ((unsigned int)f2bf(b) << 16);
}

// async global->LDS, 16B per lane. LDS dest must be wave-uniform base + lane*16.
__device__ __forceinline__ void async_copy16(const void* g, const void* l) {
    __builtin_amdgcn_global_load_lds(
        (const __attribute__((address_space(1))) unsigned int*)(unsigned long long)g,
        (__attribute__((address_space(3))) unsigned int*)(unsigned int)(unsigned long long)l,
        16, 0, 0);
}

#define MFMA_BF16(a, b, c) __builtin_amdgcn_mfma_f32_16x16x32_bf16((a), (b), (c), 0, 0, 0)
// v_mfma_f32_16x16x16_bf16 (cdna4_isa.md §10: A=2, B=2, C/D=4 regs).
// NOTE: do NOT guard with __has_builtin — false in the HIP host pass (r6 lesson).
#define MFMA16(a, b, c) __builtin_amdgcn_mfma_f32_16x16x16bf16_1k((a), (b), (c), 0, 0, 0)

// ---------------------------------------------------------------------------
// Transpose + fp32->bf16 cast: src [rows][cols] f32 -> dst [cols][rows] bf16
// ---------------------------------------------------------------------------
__global__ __launch_bounds__(256)
void transpose_cvt(const float* __restrict__ src, unsigned short* __restrict__ dst,
                   int rows, int cols) {
    __shared__ float tile[32][33];
    const int c0 = blockIdx.x * 32, r0 = blockIdx.y * 32;
    const int tx = threadIdx.x & 31, ty = threadIdx.x >> 5;  // 32 x 8
    for (int i = 0; i < 4; ++i) {
        int r = ty + i * 8;
        tile[r][tx] = src[(size_t)(r0 + r) * cols + c0 + tx];
    }
    __syncthreads();
    for (int i = 0; i < 4; ++i) {
        int rr = ty + i * 8;  // col index in src
        dst[(size_t)(c0 + rr) * rows + r0 + tx] = f2bf(tile[tx][rr]);
    }
}

// ---------------------------------------------------------------------------
// LayerNorm: x [4096][1024] f32 -> xn bf16
// ---------------------------------------------------------------------------
__global__ __launch_bounds__(256)
void ln_kernel(const float* __restrict__ x, const float* __restrict__ gamma,
               const float* __restrict__ lnb, unsigned short* __restrict__ xn) {
    const int row = blockIdx.x;
    const int tid = threadIdx.x;
    const float* xr = x + (size_t)row * DIM;
    float4 v = ((const float4*)xr)[tid];
    float s = v.x + v.y + v.z + v.w;
    float s2 = v.x * v.x + v.y * v.y + v.z * v.z + v.w * v.w;
    for (int off = 1; off < 64; off <<= 1) {
        s += __shfl_xor(s, off, 64);
        s2 += __shfl_xor(s2, off, 64);
    }
    __shared__ float red[8];
    const int wave = tid >> 6, lane = tid & 63;
    if (lane == 0) { red[wave] = s; red[4 + wave] = s2; }
    __syncthreads();
    s = red[0] + red[1] + red[2] + red[3];
    s2 = red[4] + red[5] + red[6] + red[7];
    const float mu = s * (1.0f / DIM);
    const float var = s2 * (1.0f / DIM) - mu * mu;
    const float rstd = rsqrtf(var + 1e-5f);
    float4 g = ((const float4*)gamma)[tid];
    float4 bb = ((const float4*)lnb)[tid];
    unsigned short* o = xn + (size_t)row * DIM + tid * 4;
    o[0] = f2bf((v.x - mu) * rstd * g.x + bb.x);
    o[1] = f2bf((v.y - mu) * rstd * g.y + bb.y);
    o[2] = f2bf((v.z - mu) * rstd * g.z + bb.z);
    o[3] = f2bf((v.w - mu) * rstd * g.w + bb.w);
}

// ---------------------------------------------------------------------------
// QKV GEMM (BT form): A=xn [4096][1024], Bt=wqkvT [3072][1024], both bf16.
// Scatters q,k -> [b,h,s,hd]; v -> [b,h,hd,s] (transposed for attention PV).
// ---------------------------------------------------------------------------
__global__ __launch_bounds__(256)
void qkv_gemm(const unsigned short* __restrict__ A, const unsigned short* __restrict__ Bt,
              const float* __restrict__ bias, unsigned short* __restrict__ qo,
              unsigned short* __restrict__ ko, unsigned short* __restrict__ vTo) {
    __shared__ unsigned short Asm[128 * 32];
    __shared__ unsigned short Bsm[128 * 32];
    const int tid = threadIdx.x;
    const int wave = tid >> 6, lane = tid & 63;
    const int quad = lane >> 4, r16 = lane & 15;
    const int m0 = blockIdx.y * 128, n0 = blockIdx.x * 128;
    const int wm = (wave & 1) * 64, wn = (wave >> 1) * 64;
    floatx4 acc[4][4] = {};
    for (int k0 = 0; k0 < DIM; k0 += 32) {
        __syncthreads();
        for (int p = 0; p < 2; ++p) {
            int s = tid + p * 256;
            int r = s >> 2, c8 = (s & 3) << 3;
            async_copy16(A + (size_t)(m0 + r) * DIM + k0 + c8, Asm + s * 8);
            async_copy16(Bt + (size_t)(n0 + r) * DIM + k0 + c8, Bsm + s * 8);
        }
        __syncthreads();
        bf16x8 af[4], bfr[4];
        for (int i = 0; i < 4; ++i)
            af[i] = *(const bf16x8*)(Asm + (wm + i * 16 + r16) * 32 + quad * 8);
        for (int j = 0; j < 4; ++j)
            bfr[j] = *(const bf16x8*)(Bsm + (wn + j * 16 + r16) * 32 + quad * 8);
        for (int i = 0; i < 4; ++i)
            for (int j = 0; j < 4; ++j)
                acc[i][j] = MFMA_BF16(af[i], bfr[j], acc[i][j]);
    }
    for (int j = 0; j < 4; ++j) {
        int n = n0 + wn + j * 16 + r16;
        float bn = bias[n];
        int part = n >> 10, nn = n & 1023;
        int head = nn >> 6, hdi = nn & 63;
        for (int i = 0; i < 4; ++i) {
            int mbase = m0 + wm + i * 16 + quad * 4;
            int bIdx = mbase >> 11, sIdx = mbase & 2047;
            if (part == 2) {
                ushortx4 pack;
                for (int e = 0; e < 4; ++e) pack[e] = f2bf(acc[i][j][e] + bn);
                *(ushortx4*)(vTo + ((size_t)(bIdx * NHEAD + head) * HDIM + hdi) * SEQ + sIdx) = pack;
            } else {
                unsigned short* dst = (part == 0) ? qo : ko;
                for (int e = 0; e < 4; ++e)
                    dst[((size_t)(bIdx * NHEAD + head) * SEQ + sIdx + e) * HDIM + hdi] =
                        f2bf(acc[i][j][e] + bn);
            }
        }
    }
}

// ---------------------------------------------------------------------------
// Flash attention, round-9: r7 register-direct-P loop + r5's occupancy
// mechanism (global 2-way K-split), bias table back in LDS (lgkmcnt —
// r8 showed global bias loads serialize against the vmcnt FIFO shared with
// global_load_lds prefetches, defeating the double buffer).
//  - grid (SEQ/128, B*NHEAD, 2), 256 threads; block ks handles keys
//    [ks*1024,(ks+1)*1024) over 16 double-buffered chunks.
//  - S^T = K·Q^T; P consumed direct from regs (16x16x16 B-operand ==
//    S^T C-layout); O^T = V^T·P^T; l via ones-A-frag; XOR-swizzled LDS.
//  - bias: plain float Ff[2048] in LDS (8 KB); monotone-path reads are 4
//    adjacent scalars -> ds_read2_b32 pairs.
//  - LDS = 16+16+8 = 40960 B -> 4 blocks/CU; grid 1024 = 4*256 co-resident
//    -> 16 waves/CU. launch_bounds(256,4); r7 VGPR=92 < 128 cap.
//  - partials (o bf16, l f32) to ws; combine kernel merges (fixed-offset
//    softmax -> merge is pure add).
// ---------------------------------------------------------------------------
__global__ __launch_bounds__(256, 4)
void attn_kernel(const unsigned short* __restrict__ qg, const unsigned short* __restrict__ kg,
                 const unsigned short* __restrict__ vTg, const float* __restrict__ betap,
                 unsigned short* __restrict__ opart, float* __restrict__ lpart) {
    __shared__ unsigned short Kd[2][4096];   // swizzled, rows = chunk-local key
    __shared__ unsigned short Vd[2][4096];   // swizzled, rows = d (V^T)
    __shared__ float Ff[SEQ];                // f(d) = beta*log1p(d)*log2e - 20

    const int tid = threadIdx.x;
    const int wave = tid >> 6, lane = tid & 63;
    const int quad = lane >> 4, r16 = lane & 15;
    const int bh = blockIdx.y, qt = blockIdx.x, ks = blockIdx.z;
    const int qBase = qt * 128;
    const int kBase = ks << 10;
    const float betaV = betap[0];
    const float L2E = 1.44269504f;
    const float c1 = 0.125f * L2E;

    for (int t = tid; t < SEQ; t += 256)
        Ff[t] = betaV * log1pf((float)t) * L2E - 20.0f;

    // Q fragments direct from global: B-operand (n=r16 -> q row, k octet = quad)
    bf16x8 qf[2][2];
    {
        const unsigned short* qp0 =
            qg + ((size_t)bh * SEQ + qBase + wave * 32 + r16) * HDIM;
        qf[0][0] = *(const bf16x8*)(qp0 + quad * 8);
        qf[0][1] = *(const bf16x8*)(qp0 + 32 + quad * 8);
        const unsigned short* qp1 = qp0 + 16 * HDIM;
        qf[1][0] = *(const bf16x8*)(qp1 + quad * 8);
        qf[1][1] = *(const bf16x8*)(qp1 + 32 + quad * 8);
    }

    // async-stage chunk 0 (swizzle: row r, colgrp cg stored at slot cg^(r&7))
    const int sr = tid >> 3;                  // 0..31
    const int scg = (tid & 7) ^ (sr & 7);
    const unsigned short* kbh = kg + (size_t)bh * SEQ * HDIM;
    const unsigned short* vbh = vTg + (size_t)bh * HDIM * SEQ;
    async_copy16(kbh + (size_t)(kBase + sr) * HDIM + scg * 8, &Kd[0][tid * 8]);
    async_copy16(kbh + (size_t)(kBase + sr + 32) * HDIM + scg * 8, &Kd[0][2048 + tid * 8]);
    async_copy16(vbh + (size_t)sr * SEQ + kBase + scg * 8, &Vd[0][tid * 8]);
    async_copy16(vbh + (size_t)(sr + 32) * SEQ + kBase + scg * 8, &Vd[0][2048 + tid * 8]);
    __syncthreads();

    const bf16x4 ones4 = {0x3F80, 0x3F80, 0x3F80, 0x3F80};

    floatx4 o[2][4] = {};   // O^T accum: [qn][nt], lane: q=r16, d=nt*16+quad*4+i
    floatx4 o4[2] = {};     // row-sum l (ones trick)
    const int qWB0 = qBase + wave * 32;          // wave-uniform, qn=0
    const int qrow0 = qWB0 + r16;                // per-lane query, qn=0

    for (int it = 0; it < 16; ++it) {
        const int buf = it & 1;
        const int kt0 = kBase + (it << 6);
        if (it + 1 < 16) {
            const int nk = kt0 + 64;
            async_copy16(kbh + (size_t)(nk + sr) * HDIM + scg * 8, &Kd[buf ^ 1][tid * 8]);
            async_copy16(kbh + (size_t)(nk + sr + 32) * HDIM + scg * 8, &Kd[buf ^ 1][2048 + tid * 8]);
            async_copy16(vbh + (size_t)sr * SEQ + nk + scg * 8, &Vd[buf ^ 1][tid * 8]);
            async_copy16(vbh + (size_t)(sr + 32) * SEQ + nk + scg * 8, &Vd[buf ^ 1][2048 + tid * 8]);
        }

        // S^T = K·Q^T, K frags shared across both q-groups
        floatx4 sc[2][4];
        for (int ct = 0; ct < 4; ++ct) {
            int rK = ct * 16 + r16;
            const unsigned short* kb = &Kd[buf][rK * 64];
            bf16x8 kf0 = *(const bf16x8*)(kb + ((quad ^ (rK & 7)) << 3));
            bf16x8 kf1 = *(const bf16x8*)(kb + (((quad ^ 4) ^ (rK & 7)) << 3));
            for (int qn = 0; qn < 2; ++qn) {
                floatx4 z = {0.f, 0.f, 0.f, 0.f};
                z = MFMA_BF16(kf0, qf[qn][0], z);
                z = MFMA_BF16(kf1, qf[qn][1], z);
                sc[qn][ct] = z;
            }
        }
        // bias (LDS table, adjacent scalars -> ds_read2_b32) + exp2 -> packed P
        bf16x4 pk[2][4];
        for (int qn = 0; qn < 2; ++qn) {
            const int qWB = qWB0 + qn * 16;
            const int qrow = qrow0 + qn * 16;
            for (int ct = 0; ct < 4; ++ct) {
                const int keyTile = kt0 + ct * 16;   // wave-uniform
                const int key0 = keyTile + quad * 4; // per-lane key base
                floatx4 s = sc[qn][ct];
                if (qWB >= keyTile + 16) {            // all queries > all keys
                    const float* lp = &Ff[qrow - key0 - 3];
                    for (int i = 0; i < 4; ++i)
                        s[i] = __builtin_amdgcn_exp2f(s[i] * c1 + lp[3 - i]);
                } else if (keyTile >= qWB + 16) {     // all keys > all queries
                    const float* lp = &Ff[key0 - qrow];
                    for (int i = 0; i < 4; ++i)
                        s[i] = __builtin_amdgcn_exp2f(s[i] * c1 + lp[i]);
                } else {                               // mixed (diagonal tiles)
                    for (int i = 0; i < 4; ++i) {
                        int d = key0 + i - qrow;
                        d = d < 0 ? -d : d;
                        s[i] = __builtin_amdgcn_exp2f(s[i] * c1 + Ff[d]);
                    }
                }
                intx2 u = {(int)pack_bf16(s[0], s[1]), (int)pack_bf16(s[2], s[3])};
                pk[qn][ct] = __builtin_bit_cast(bf16x4, u);
            }
        }
        // O^T += V^T·P^T  (MFMA16; V^T frags shared across q-groups)
        for (int kss = 0; kss < 4; ++kss) {
            o4[0] = MFMA16(ones4, pk[0][kss], o4[0]);
            o4[1] = MFMA16(ones4, pk[1][kss], o4[1]);
            for (int nt = 0; nt < 4; ++nt) {
                int rV = nt * 16 + r16;
                const unsigned short* vb = &Vd[buf][rV * 64];
                bf16x4 vf = *(const bf16x4*)(vb +
                    (((kss * 2 + (quad >> 1)) ^ (rV & 7)) << 3) + ((quad & 1) << 2));
                o[0][nt] = MFMA16(vf, pk[0][kss], o[0][nt]);
                o[1][nt] = MFMA16(vf, pk[1][kss], o[1][nt]);
            }
        }
        __syncthreads();
    }

    // partial epilogue: lane holds O^T[d=nt*16+quad*4+i][q=r16] -> packed 8B
    unsigned short* op = opart + (size_t)ks * NTOK * DIM;
    const int b_ = bh >> 4, h_ = bh & 15;
    for (int qn = 0; qn < 2; ++qn) {
        int q = qBase + wave * 32 + qn * 16 + r16;
        size_t rowoff = ((size_t)(b_ * SEQ + q)) * DIM + h_ * HDIM;
        for (int nt = 0; nt < 4; ++nt) {
            ushortx4 pck;
            for (int i = 0; i < 4; ++i) pck[i] = f2bf(o[qn][nt][i]);
            *(ushortx4*)(op + rowoff + nt * 16 + quad * 4) = pck;
        }
        if (quad == 0)
            lpart[(size_t)ks * NHEAD * 2 * SEQ + (size_t)bh * SEQ + q] = o4[qn][0];
    }
}

// ---------------------------------------------------------------------------
// Combine K-split partials: ctx = (oA + oB) / (lA + lB), written in-place
// over the oB region (which then serves as ctx for out_gemm).
// ---------------------------------------------------------------------------
__global__ __launch_bounds__(256)
void attn_combine(const unsigned short* __restrict__ oA, unsigned short* __restrict__ oB,
                  const float* __restrict__ lA, const float* __restrict__ lB) {
    const int row = blockIdx.x;            // b*2048 + q
    const int col = threadIdx.x * 4;
    const int b_ = row >> 11, q = row & 2047;
    const int head = col >> 6;
    const int li = (b_ * NHEAD + head) * SEQ + q;
    const float inv = 1.0f / (lA[li] + lB[li]);
    const size_t off = (size_t)row * DIM + col;
    ushortx4 a = *(const ushortx4*)(oA + off);
    ushortx4 b = *(const ushortx4*)(oB + off);
    ushortx4 r;
    for (int i = 0; i < 4; ++i) {
        float fa = __builtin_bit_cast(float, (unsigned int)(unsigned short)a[i] << 16);
        float fb = __builtin_bit_cast(float, (unsigned int)(unsigned short)b[i] << 16);
        r[i] = f2bf((fa + fb) * inv);
    }
    *(ushortx4*)(oB + off) = r;
}

// ---------------------------------------------------------------------------
// Out projection + bias + residual: out = ctx @ w_out + b_out + x  (fp32 out)
// 128(M)x64(N) tiles -> 512 blocks (2/CU).
// ---------------------------------------------------------------------------
__global__ __launch_bounds__(256)
void out_gemm(const unsigned short* __restrict__ A, const unsigned short* __restrict__ Bt,
              const float* __restrict__ bias, const float* __restrict__ resid,
              float* __restrict__ out) {
    __shared__ unsigned short Asm[128 * 32];
    __shared__ unsigned short Bsm[64 * 32];
    const int tid = threadIdx.x;
    const int wave = tid >> 6, lane = tid & 63;
    const int quad = lane >> 4, r16 = lane & 15;
    const int m0 = blockIdx.y * 128, n0 = blockIdx.x * 64;
    const int wm = (wave & 1) * 64, wn = (wave >> 1) * 32;
    floatx4 acc[4][2] = {};
    for (int k0 = 0; k0 < DIM; k0 += 32) {
        __syncthreads();
        for (int p = 0; p < 2; ++p) {
            int s = tid + p * 256;
            int r = s >> 2, c8 = (s & 3) << 3;
            async_copy16(A + (size_t)(m0 + r) * DIM + k0 + c8, Asm + s * 8);
        }
        {
            int r = tid >> 2, c8 = (tid & 3) << 3;
            async_copy16(Bt + (size_t)(n0 + r) * DIM + k0 + c8, Bsm + tid * 8);
        }
        __syncthreads();
        bf16x8 af[4], bfr[2];
        for (int i = 0; i < 4; ++i)
            af[i] = *(const bf16x8*)(Asm + (wm + i * 16 + r16) * 32 + quad * 8);
        for (int j = 0; j < 2; ++j)
            bfr[j] = *(const bf16x8*)(Bsm + (wn + j * 16 + r16) * 32 + quad * 8);
        for (int i = 0; i < 4; ++i)
            for (int j = 0; j < 2; ++j)
                acc[i][j] = MFMA_BF16(af[i], bfr[j], acc[i][j]);
    }
    for (int i = 0; i < 4; ++i)
        for (int j = 0; j < 2; ++j)
            for (int e = 0; e < 4; ++e) {
                int m = m0 + wm + i * 16 + quad * 4 + e;
                int n = n0 + wn + j * 16 + r16;
                out[(size_t)m * DIM + n] = acc[i][j][e] + bias[n] + resid[(size_t)m * DIM + n];
            }
}

// ---------------------------------------------------------------------------
extern "C" void kernel_launch(void* const* d_in, const int* in_sizes, int n_in,
                              void* d_out, int out_size, void* d_ws, size_t ws_size,
                              hipStream_t stream) {
    const float* x     = (const float*)d_in[0];
    const float* w_qkv = (const float*)d_in[1];
    const float* b_qkv = (const float*)d_in[2];
    const float* w_out = (const float*)d_in[3];
    const float* b_out = (const float*)d_in[4];
    const float* gamma = (const float*)d_in[5];
    const float* ln_b  = (const float*)d_in[6];
    const float* beta  = (const float*)d_in[7];
    float* out = (float*)d_out;

    char* ws = (char*)d_ws;
    const size_t MB = 1u << 20;
    // [0,8): xn (dead after qkv) -> oA partial
    // [8,16): oB partial -> combined in-place -> ctx
    // [16,22): wqkvT (dead after qkv) -> overlaid by l partials (512 KB)
    // [22,24): woutT ; [24,32): qb ; [32,40): kb ; [40,48): vTb
    unsigned short* xn    = (unsigned short*)(ws);
    unsigned short* oA    = (unsigned short*)(ws);
    unsigned short* oB    = (unsigned short*)(ws + 8 * MB);   // becomes ctx
    unsigned short* wqkvT = (unsigned short*)(ws + 16 * MB);
    float*          lprt  = (float*)(ws + 16 * MB);
    unsigned short* woutT = (unsigned short*)(ws + 22 * MB);
    unsigned short* qb    = (unsigned short*)(ws + 24 * MB);
    unsigned short* kb    = (unsigned short*)(ws + 32 * MB);
    unsigned short* vTb   = (unsigned short*)(ws + 40 * MB);

    transpose_cvt<<<dim3(96, 32), 256, 0, stream>>>(w_qkv, wqkvT, DIM, N3D);
    transpose_cvt<<<dim3(32, 32), 256, 0, stream>>>(w_out, woutT, DIM, DIM);
    ln_kernel<<<NTOK, 256, 0, stream>>>(x, gamma, ln_b, xn);
    qkv_gemm<<<dim3(24, 32), 256, 0, stream>>>(xn, wqkvT, b_qkv, qb, kb, vTb);
    attn_kernel<<<dim3(SEQ / 128, 32, 2), 256, 0, stream>>>(qb, kb, vTb, beta, oA, lprt);
    attn_combine<<<NTOK, 256, 0, stream>>>(oA, oB, lprt, lprt + 32 * SEQ);
    out_gemm<<<dim3(16, 32), 256, 0, stream>>>(oB, woutT, b_out, x, out);
}